// Round 5
// baseline (190.646 us; speedup 1.0000x reference)
//
#include <hip/hip_runtime.h>
#include <hip/hip_fp16.h>

// Sinkhorn (B=64, R=1024, C=1024, fp32, TAU=1, MAX_ITER=10), linear space,
// fused row+col pairs. E[b][r][c] = exp(s) cached fp16 (512 row slots).
//   a[r]  = 1 / Σ_{c<nc} E[r,c] * w_prev[c]   (w_prev = 1/cs_prev, iter0: 1)
//   cs[c] = Σ_{r<nr} E[r,c] * a[r]            (split-K atomics per 64-row chunk)
// One kernel per (row,col) pair: block = (batch, 64-row chunk).
//   phase 1: 8 waves x 8 rows -> a for the chunk (LDS + global)
//   phase 2: 512 threads x 2 cols x 64 rows -> atomicAdd into cs_cur
// cs uses 3 rotating buffers; kernel i zeroes cs_next for kernel i+1 (safe:
// cs_next is idle during kernel i). out = E * a[r] / cs_final[c] on valid.

#define B_DIM 64

__device__ __forceinline__ float fast_rcp(float x) {
#if __has_builtin(__builtin_amdgcn_rcpf)
    return __builtin_amdgcn_rcpf(x);
#else
    return 1.0f / x;
#endif
}

__device__ __forceinline__ float wave_sum(float x) {
    #pragma unroll
    for (int off = 1; off < 64; off <<= 1) x += __shfl_xor(x, off);
    return x;
}

// ---------------- fused pair kernels: grid (8, B), block 512 ----------------

// Common phase-2 + epilogue, shared by both kernels via inlining.
__device__ __forceinline__ void phase2_col(
    const __half* __restrict__ E, const float* a_lds, int b, int r0, int nr,
    int nc, int t, float* __restrict__ cs_cur)
{
    if (r0 >= nr) return;
    const int c0 = t << 1;
    if (c0 >= nc) return;
    const int rend = min(r0 + 64, nr);
    const __half* __restrict__ Eb = E + ((size_t)b << 19) + c0;

    float sA0 = 0.f, sA1 = 0.f, sB0 = 0.f, sB1 = 0.f;
    int r = r0;
    for (; r + 4 <= rend; r += 4) {
        const float2 f0 = __half22float2(*reinterpret_cast<const __half2*>(Eb + ((size_t)(r + 0) << 10)));
        const float2 f1 = __half22float2(*reinterpret_cast<const __half2*>(Eb + ((size_t)(r + 1) << 10)));
        const float2 f2 = __half22float2(*reinterpret_cast<const __half2*>(Eb + ((size_t)(r + 2) << 10)));
        const float2 f3 = __half22float2(*reinterpret_cast<const __half2*>(Eb + ((size_t)(r + 3) << 10)));
        const float a0 = a_lds[r + 0 - r0], a1 = a_lds[r + 1 - r0];
        const float a2 = a_lds[r + 2 - r0], a3 = a_lds[r + 3 - r0];
        sA0 = fmaf(f0.x, a0, sA0); sA1 = fmaf(f0.y, a0, sA1);
        sB0 = fmaf(f1.x, a1, sB0); sB1 = fmaf(f1.y, a1, sB1);
        sA0 = fmaf(f2.x, a2, sA0); sA1 = fmaf(f2.y, a2, sA1);
        sB0 = fmaf(f3.x, a3, sB0); sB1 = fmaf(f3.y, a3, sB1);
    }
    for (; r < rend; ++r) {
        const float2 f = __half22float2(*reinterpret_cast<const __half2*>(Eb + ((size_t)r << 10)));
        const float av = a_lds[r - r0];
        sA0 = fmaf(f.x, av, sA0); sA1 = fmaf(f.y, av, sA1);
    }
    atomicAdd(cs_cur + (b << 10) + c0, sA0 + sB0);
    if (c0 + 1 < nc)
        atomicAdd(cs_cur + (b << 10) + c0 + 1, sA1 + sB1);
}

// Pair 0: reads s fp32, writes E = exp(s), row sums with w=1, col atomics.
__global__ __launch_bounds__(512) void pair_first(
    const float* __restrict__ s, const int* __restrict__ nrows,
    const int* __restrict__ ncols, __half* __restrict__ E,
    float* __restrict__ a, float* __restrict__ cs_cur,
    float* __restrict__ cs_next)
{
    const int b = blockIdx.y;
    const int rc = blockIdx.x;
    const int t = threadIdx.x;
    if (t < 128) cs_next[(b << 10) + (rc << 7) + t] = 0.f;

    const int nr = nrows[b];
    const int nc = ncols[b];
    const int r0 = rc << 6;
    __shared__ float a_lds[64];

    const int wave = t >> 6;
    const int lane = t & 63;
    const int cbase = lane << 4;   // 16 cols per lane
    const int nv = min(max(nc - cbase, 0), 16);

    if (r0 < nr) {
        #pragma unroll 1
        for (int k = 0; k < 8; ++k) {
            const int r = r0 + (wave << 3) + k;
            float s0 = 0.f, s1 = 0.f;
            if (r < nr) {
                const float* __restrict__ srow =
                    s + ((size_t)b << 20) + ((size_t)r << 10) + cbase;
                __half* __restrict__ erow =
                    E + ((size_t)b << 19) + ((size_t)r << 10) + cbase;
                float e[16];
                #pragma unroll
                for (int q = 0; q < 4; ++q) {
                    const float4 x = *reinterpret_cast<const float4*>(srow + (q << 2));
                    e[4 * q + 0] = __expf(x.x); e[4 * q + 1] = __expf(x.y);
                    e[4 * q + 2] = __expf(x.z); e[4 * q + 3] = __expf(x.w);
                }
                __half2 h[8];
                #pragma unroll
                for (int q = 0; q < 8; ++q)
                    h[q] = __floats2half2_rn(e[2 * q], e[2 * q + 1]);
                *reinterpret_cast<float4*>(erow)     = *reinterpret_cast<float4*>(&h[0]);
                *reinterpret_cast<float4*>(erow + 8) = *reinterpret_cast<float4*>(&h[4]);
                #pragma unroll
                for (int j = 0; j < 16; j += 2) {
                    s0 += (j < nv) ? e[j] : 0.f;
                    s1 += (j + 1 < nv) ? e[j + 1] : 0.f;
                }
            }
            const float sum = wave_sum(s0 + s1);
            if (lane == 0) a_lds[(wave << 3) + k] = (r < nr) ? 1.0f / sum : 0.f;
        }
    } else if (t < 64) {
        a_lds[t] = 0.f;
    }
    __syncthreads();
    if (t < 64) a[(b << 9) + r0 + t] = a_lds[t];

    phase2_col(E, a_lds, b, r0, nr, nc, t, cs_cur);
}

// Pairs 1..4: reads E, w = 1/cs_prev.
__global__ __launch_bounds__(512) void pair_mid(
    const __half* __restrict__ E, const int* __restrict__ nrows,
    const int* __restrict__ ncols, const float* __restrict__ cs_prev,
    float* __restrict__ a, float* __restrict__ cs_cur,
    float* __restrict__ cs_next)
{
    const int b = blockIdx.y;
    const int rc = blockIdx.x;
    const int t = threadIdx.x;
    if (t < 128) cs_next[(b << 10) + (rc << 7) + t] = 0.f;

    const int nr = nrows[b];
    const int nc = ncols[b];
    const int r0 = rc << 6;
    __shared__ float a_lds[64];

    const int wave = t >> 6;
    const int lane = t & 63;
    const int cbase = lane << 4;

    if (r0 < nr) {
        // per-lane column weights, hoisted across the 8 rows
        float w[16];
        const float* __restrict__ csp = cs_prev + (b << 10) + cbase;
        #pragma unroll
        for (int q = 0; q < 4; ++q) {
            const float4 c4 = *reinterpret_cast<const float4*>(csp + (q << 2));
            w[4 * q + 0] = (cbase + 4 * q + 0 < nc) ? fast_rcp(c4.x) : 0.f;
            w[4 * q + 1] = (cbase + 4 * q + 1 < nc) ? fast_rcp(c4.y) : 0.f;
            w[4 * q + 2] = (cbase + 4 * q + 2 < nc) ? fast_rcp(c4.z) : 0.f;
            w[4 * q + 3] = (cbase + 4 * q + 3 < nc) ? fast_rcp(c4.w) : 0.f;
        }
        #pragma unroll 1
        for (int k = 0; k < 8; ++k) {
            const int r = r0 + (wave << 3) + k;
            float s0 = 0.f, s1 = 0.f;
            if (r < nr) {
                const __half* __restrict__ erow =
                    E + ((size_t)b << 19) + ((size_t)r << 10) + cbase;
                float4 p0 = *reinterpret_cast<const float4*>(erow);      // 8 half
                float4 p1 = *reinterpret_cast<const float4*>(erow + 8);  // 8 half
                const __half2* h0 = reinterpret_cast<const __half2*>(&p0);
                const __half2* h1 = reinterpret_cast<const __half2*>(&p1);
                #pragma unroll
                for (int q = 0; q < 4; ++q) {
                    const float2 f = __half22float2(h0[q]);
                    s0 = fmaf(f.x, w[2 * q], s0);
                    s1 = fmaf(f.y, w[2 * q + 1], s1);
                }
                #pragma unroll
                for (int q = 0; q < 4; ++q) {
                    const float2 f = __half22float2(h1[q]);
                    s0 = fmaf(f.x, w[8 + 2 * q], s0);
                    s1 = fmaf(f.y, w[8 + 2 * q + 1], s1);
                }
            }
            const float sum = wave_sum(s0 + s1);
            if (lane == 0) a_lds[(wave << 3) + k] = (r < nr) ? 1.0f / sum : 0.f;
        }
    } else if (t < 64) {
        a_lds[t] = 0.f;
    }
    __syncthreads();
    if (t < 64) a[(b << 9) + r0 + t] = a_lds[t];

    phase2_col(E, a_lds, b, r0, nr, nc, t, cs_cur);
}

// grid (65536), block 256. One float4 of output per thread.
__global__ __launch_bounds__(256) void out_step_f(
    const __half* __restrict__ E, const int* __restrict__ nrows,
    const int* __restrict__ ncols, const float* __restrict__ a,
    const float* __restrict__ cs, float* __restrict__ out)
{
    const int g = (blockIdx.x << 8) + threadIdx.x;  // 0..16777215
    const int b = g >> 18;
    const int rem = g & 262143;
    const int r = rem >> 8;
    const int c0 = (rem & 255) << 2;
    const int nr = nrows[b];
    const int nc = ncols[b];
    float4 o = make_float4(0.f, 0.f, 0.f, 0.f);
    if (r < nr && c0 < nc) {
        const float ar = a[(b << 9) + r];
        float2 pk = *reinterpret_cast<const float2*>(
            E + ((size_t)b << 19) + ((size_t)r << 10) + c0);
        const float2 f01 = __half22float2(reinterpret_cast<const __half2*>(&pk)[0]);
        const float2 f23 = __half22float2(reinterpret_cast<const __half2*>(&pk)[1]);
        const float4 c4 = *reinterpret_cast<const float4*>(cs + (b << 10) + c0);
        o.x = f01.x * ar * fast_rcp(c4.x);
        o.y = (c0 + 1 < nc) ? f01.y * ar * fast_rcp(c4.y) : 0.f;
        o.z = (c0 + 2 < nc) ? f23.x * ar * fast_rcp(c4.z) : 0.f;
        o.w = (c0 + 3 < nc) ? f23.y * ar * fast_rcp(c4.w) : 0.f;
    }
    reinterpret_cast<float4*>(out)[g] = o;
}

// ==================== legacy path (small workspace) =========================

__global__ __launch_bounds__(256) void row_step_lg(
    const float* __restrict__ s, const int* __restrict__ nrows,
    const int* __restrict__ ncols, const float* __restrict__ vlog,
    const int use_v, float* __restrict__ u)
{
    const int b = blockIdx.y, r = blockIdx.x;
    const int nr = nrows[b];
    if (r >= nr) return;
    const int nc = ncols[b];
    const int t = threadIdx.x, c0 = t << 2;
    float sum = 0.f;
    if (c0 < nc) {
        const float4 x = reinterpret_cast<const float4*>(
            s + ((size_t)b << 20) + ((size_t)r << 10))[t];
        float4 vv = make_float4(0.f, 0.f, 0.f, 0.f);
        if (use_v) vv = reinterpret_cast<const float4*>(vlog + ((size_t)b << 10))[t];
        sum  = (c0 + 0 < nc) ? __expf(x.x - vv.x) : 0.f;
        sum += (c0 + 1 < nc) ? __expf(x.y - vv.y) : 0.f;
        sum += (c0 + 2 < nc) ? __expf(x.z - vv.z) : 0.f;
        sum += (c0 + 3 < nc) ? __expf(x.w - vv.w) : 0.f;
    }
    #pragma unroll
    for (int off = 1; off < 64; off <<= 1) sum += __shfl_xor(sum, off);
    __shared__ float ss[4];
    if ((t & 63) == 0) ss[t >> 6] = sum;
    __syncthreads();
    if (t == 0) u[((size_t)b << 9) + r] = __logf(ss[0] + ss[1] + ss[2] + ss[3]);
}

__global__ __launch_bounds__(256) void col_step_lg(
    const float* __restrict__ s, const int* __restrict__ nrows,
    const int* __restrict__ ncols, const float* __restrict__ u,
    float* __restrict__ partial)
{
    const int b = blockIdx.z, rc = blockIdx.y;
    const int nr = nrows[b];
    const int r0 = rc << 6;
    if (r0 >= nr) return;
    const int nc = ncols[b];
    const int c = (blockIdx.x << 8) + threadIdx.x;
    float sum = 0.f;
    if (c < nc) {
        const int rend = min(r0 + 64, nr);
        const float* __restrict__ sb = s + ((size_t)b << 20) + c;
        const float* __restrict__ ub = u + ((size_t)b << 9);
        float s0 = 0.f, s1 = 0.f, s2 = 0.f, s3 = 0.f;
        int r = r0;
        for (; r + 4 <= rend; r += 4) {
            s0 += __expf(sb[(size_t)(r + 0) << 10] - ub[r + 0]);
            s1 += __expf(sb[(size_t)(r + 1) << 10] - ub[r + 1]);
            s2 += __expf(sb[(size_t)(r + 2) << 10] - ub[r + 2]);
            s3 += __expf(sb[(size_t)(r + 3) << 10] - ub[r + 3]);
        }
        for (; r < rend; ++r) s0 += __expf(sb[(size_t)r << 10] - ub[r]);
        sum = (s0 + s1) + (s2 + s3);
    }
    partial[(((size_t)b << 3) + rc) << 10 | c] = sum;
}

__global__ __launch_bounds__(256) void col_fin_lg(
    const int* __restrict__ nrows, const float* __restrict__ partial,
    float* __restrict__ vlog)
{
    const int idx = (blockIdx.x << 8) + threadIdx.x;
    const int b = idx >> 10;
    const int nch = (nrows[b] + 63) >> 6;
    const float* __restrict__ p = partial + ((size_t)(b << 3) << 10) + (idx & 1023);
    float sum = 0.f;
    for (int k = 0; k < nch; ++k) sum += p[(size_t)k << 10];
    vlog[idx] = (sum > 0.f) ? __logf(sum) : 0.f;
}

__global__ __launch_bounds__(256) void out_step_lg(
    const float* __restrict__ s, const int* __restrict__ nrows,
    const int* __restrict__ ncols, const float* __restrict__ u,
    const float* __restrict__ vlog, float* __restrict__ out)
{
    const size_t total4 = (size_t)B_DIM * 1024 * 1024 / 4;
    float4* out4 = reinterpret_cast<float4*>(out);
    const float4* s4 = reinterpret_cast<const float4*>(s);
    for (size_t i = (size_t)blockIdx.x * blockDim.x + threadIdx.x; i < total4;
         i += (size_t)gridDim.x * blockDim.x) {
        const int b = (int)(i >> 18);
        const int rem = (int)(i & 262143);
        const int r = rem >> 8;
        const int c0 = (rem & 255) << 2;
        const int nr = nrows[b], nc = ncols[b];
        float4 o;
        if (r >= nr || c0 >= nc) {
            o = make_float4(0.f, 0.f, 0.f, 0.f);
        } else {
            float4 x = s4[i];
            const float ur = u[((size_t)b << 9) + r];
            const float* vb = vlog + ((size_t)b << 10);
            o.x = (c0 + 0 < nc) ? __expf(x.x - ur - vb[c0 + 0]) : 0.f;
            o.y = (c0 + 1 < nc) ? __expf(x.y - ur - vb[c0 + 1]) : 0.f;
            o.z = (c0 + 2 < nc) ? __expf(x.z - ur - vb[c0 + 2]) : 0.f;
            o.w = (c0 + 3 < nc) ? __expf(x.w - ur - vb[c0 + 3]) : 0.f;
        }
        out4[i] = o;
    }
}

// ============================================================================

extern "C" void kernel_launch(void* const* d_in, const int* in_sizes, int n_in,
                              void* d_out, int out_size, void* d_ws, size_t ws_size,
                              hipStream_t stream) {
    const float* s = (const float*)d_in[0];
    const int* nrows = (const int*)d_in[1];
    const int* ncols = (const int*)d_in[2];
    float* out = (float*)d_out;

    const size_t E_BYTES = (size_t)B_DIM * 512 * 1024 * 2;   // 64 MiB fp16
    const size_t CS_ELEMS = (size_t)B_DIM * 1024;
    const size_t NEED = E_BYTES + (size_t)B_DIM * 512 * 4 + 3 * CS_ELEMS * 4;

    if (ws_size >= NEED) {
        __half* E = (__half*)d_ws;
        float* a = (float*)((char*)d_ws + E_BYTES);
        float* cs0 = a + B_DIM * 512;
        float* cs1 = cs0 + CS_ELEMS;
        float* cs2 = cs1 + CS_ELEMS;

        hipMemsetAsync(cs0, 0, CS_ELEMS * sizeof(float), stream);

        const dim3 grid(8, B_DIM);
        // pair i: prev=cs[(i+2)%3], cur=cs[i%3], next=cs[(i+1)%3]
        pair_first<<<grid, 512, 0, stream>>>(s, nrows, ncols, E, a, cs0, cs1);
        pair_mid<<<grid, 512, 0, stream>>>(E, nrows, ncols, cs0, a, cs1, cs2);
        pair_mid<<<grid, 512, 0, stream>>>(E, nrows, ncols, cs1, a, cs2, cs0);
        pair_mid<<<grid, 512, 0, stream>>>(E, nrows, ncols, cs2, a, cs0, cs1);
        pair_mid<<<grid, 512, 0, stream>>>(E, nrows, ncols, cs0, a, cs1, cs2);
        out_step_f<<<65536, 256, 0, stream>>>(E, nrows, ncols, a, cs1, out);
    } else {
        // legacy log-space path (needs ~2.4 MiB)
        float* u = (float*)d_ws;
        float* vlog = u + (size_t)B_DIM * 512;
        float* partial = vlog + (size_t)B_DIM * 1024;
        const dim3 rowGrid(512, B_DIM);
        const dim3 colGrid(4, 8, B_DIM);
        for (int it = 0; it < 5; ++it) {
            row_step_lg<<<rowGrid, 256, 0, stream>>>(s, nrows, ncols, vlog, it, u);
            col_step_lg<<<colGrid, 256, 0, stream>>>(s, nrows, ncols, u, partial);
            col_fin_lg<<<256, 256, 0, stream>>>(nrows, partial, vlog);
        }
        out_step_lg<<<4096, 256, 0, stream>>>(s, nrows, ncols, u, vlog, out);
    }
}

// Round 6
// 161.386 us; speedup vs baseline: 1.1813x; 1.1813x over previous
//
#include <hip/hip_runtime.h>
#include <hip/hip_fp16.h>

// Sinkhorn (B=64, R=1024, C=1024, fp32, TAU=1, MAX_ITER=10), linear space,
// fused row+col pairs. E[b][r][c] = exp(s) cached fp16 (512 row slots),
// ZEROED for c >= nc (so downstream passes need no column masking and skip
// ~25% of bytes by never touching granules with cbase >= nc).
//   a[r]  = 1 / Σ_c E[r,c] * w_prev[c]   (w_prev = 1/cs_prev, iter0: w=1)
//   cs[c] = Σ_{r<nr} E[r,c] * a[r]       (per-block LDS partials + atomics)
// Kernel per pair: block = (batch, 32-row chunk), grid (16,64), 512 thr.
//   phase 1: 8 waves x 4 rows, 16 cols/lane -> a_lds[32]
//   phase 2: thread = 8 cols (dwordx4) x 8 rows; LDS [4][1024] partials,
//            stride-1 reduce, <=2 global atomicAdd per thread.
// cs: 3 rotating buffers; kernel i zeroes cs_next for kernel i+1 (idle then).
// out = E * a[r] / cs_final[c] on valid region, else 0.

#define B_DIM 64
#define RCH 32
#define NCH 16

__device__ __forceinline__ float fast_rcp(float x) {
#if __has_builtin(__builtin_amdgcn_rcpf)
    return __builtin_amdgcn_rcpf(x);
#else
    return 1.0f / x;
#endif
}

__device__ __forceinline__ float wave_sum(float x) {
    #pragma unroll
    for (int off = 1; off < 64; off <<= 1) x += __shfl_xor(x, off);
    return x;
}

// Phase 2 (shared): col partial sums for this 32-row chunk -> atomics.
// a_lds[j] == 0 for rows >= nr kills unwritten-E rows (poison is finite).
__device__ __forceinline__ void phase2_col(
    const __half* __restrict__ E, const float* __restrict__ a_lds,
    float* __restrict__ cls,   // [4][1024] LDS
    int b, int r0, int nr, int nc, int t, float* __restrict__ cs_cur)
{
    const int c0 = (t & 127) << 3;
    const int rsub = t >> 7;                 // 0..3
    float acc0 = 0.f, acc1 = 0.f, acc2 = 0.f, acc3 = 0.f;
    float acc4 = 0.f, acc5 = 0.f, acc6 = 0.f, acc7 = 0.f;
    if (c0 < nc) {
        const int rs = r0 + (rsub << 3);
        const __half* __restrict__ Eb = E + ((size_t)b << 19) + c0;
        #pragma unroll
        for (int k = 0; k < 8; ++k) {
            const int r = rs + k;
            const float4 p = *reinterpret_cast<const float4*>(Eb + ((size_t)r << 10));
            const __half2* h = reinterpret_cast<const __half2*>(&p);
            const float av = a_lds[r - r0];      // 0 for r >= nr
            const float2 f0 = __half22float2(h[0]);
            const float2 f1 = __half22float2(h[1]);
            const float2 f2 = __half22float2(h[2]);
            const float2 f3 = __half22float2(h[3]);
            acc0 = fmaf(f0.x, av, acc0); acc1 = fmaf(f0.y, av, acc1);
            acc2 = fmaf(f1.x, av, acc2); acc3 = fmaf(f1.y, av, acc3);
            acc4 = fmaf(f2.x, av, acc4); acc5 = fmaf(f2.y, av, acc5);
            acc6 = fmaf(f3.x, av, acc6); acc7 = fmaf(f3.y, av, acc7);
        }
    }
    float* dst = cls + (rsub << 10) + c0;
    *reinterpret_cast<float4*>(dst)     = make_float4(acc0, acc1, acc2, acc3);
    *reinterpret_cast<float4*>(dst + 4) = make_float4(acc4, acc5, acc6, acc7);
    __syncthreads();
    #pragma unroll
    for (int k = 0; k < 2; ++k) {
        const int c = t + (k << 9);
        const float v = cls[c] + cls[1024 + c] + cls[2048 + c] + cls[3072 + c];
        if (v != 0.f) atomicAdd(cs_cur + (b << 10) + c, v);
    }
}

// Pair 0: reads s fp32, writes E = exp(s) (masked to 0 for c>=nc), row sums
// with w=1, then col phase. Also zeroes its slice of cs_next.
__global__ __launch_bounds__(512) void pair_first(
    const float* __restrict__ s, const int* __restrict__ nrows,
    const int* __restrict__ ncols, __half* __restrict__ E,
    float* __restrict__ a, float* __restrict__ cs_cur,
    float* __restrict__ cs_next)
{
    const int b = blockIdx.y;
    const int rc = blockIdx.x;
    const int t = threadIdx.x;
    if (t < 64) cs_next[(b << 10) + (rc << 6) + t] = 0.f;

    const int nr = nrows[b];
    const int r0 = rc << 5;
    if (r0 >= nr) return;                 // uniform, before any barrier
    const int nc = ncols[b];

    __shared__ float a_lds[RCH];
    __shared__ float cls[4 * 1024];

    const int wave = t >> 6;
    const int lane = t & 63;
    const int cbase = lane << 4;          // 16 cols per lane
    const bool cOK = cbase < nc;

    #pragma unroll 1
    for (int k = 0; k < 4; ++k) {
        const int r = r0 + (wave << 2) + k;
        float sum = 0.f;
        if (r < nr && cOK) {
            const float* __restrict__ srow =
                s + ((size_t)b << 20) + ((size_t)r << 10) + cbase;
            __half* __restrict__ erow =
                E + ((size_t)b << 19) + ((size_t)r << 10) + cbase;
            float e[16];
            #pragma unroll
            for (int q = 0; q < 4; ++q) {
                const float4 x = *reinterpret_cast<const float4*>(srow + (q << 2));
                e[4 * q + 0] = __expf(x.x); e[4 * q + 1] = __expf(x.y);
                e[4 * q + 2] = __expf(x.z); e[4 * q + 3] = __expf(x.w);
            }
            #pragma unroll
            for (int j = 0; j < 16; ++j)
                if (cbase + j >= nc) e[j] = 0.f;
            __half2 h[8];
            #pragma unroll
            for (int q = 0; q < 8; ++q)
                h[q] = __floats2half2_rn(e[2 * q], e[2 * q + 1]);
            *reinterpret_cast<float4*>(erow)     = *reinterpret_cast<const float4*>(&h[0]);
            *reinterpret_cast<float4*>(erow + 8) = *reinterpret_cast<const float4*>(&h[4]);
            #pragma unroll
            for (int j = 0; j < 16; ++j) sum += e[j];
        }
        sum = wave_sum(sum);
        if (lane == 0) a_lds[(wave << 2) + k] = (r < nr) ? 1.0f / sum : 0.f;
    }
    __syncthreads();
    if (t < RCH) a[(b << 9) + r0 + t] = a_lds[t];

    phase2_col(E, a_lds, cls, b, r0, nr, nc, t, cs_cur);
}

// Pairs 1..4: reads E, w = 1/cs_prev (guarded per column), then col phase.
__global__ __launch_bounds__(512) void pair_mid(
    const __half* __restrict__ E, const int* __restrict__ nrows,
    const int* __restrict__ ncols, const float* __restrict__ cs_prev,
    float* __restrict__ a, float* __restrict__ cs_cur,
    float* __restrict__ cs_next)
{
    const int b = blockIdx.y;
    const int rc = blockIdx.x;
    const int t = threadIdx.x;
    if (t < 64) cs_next[(b << 10) + (rc << 6) + t] = 0.f;

    const int nr = nrows[b];
    const int r0 = rc << 5;
    if (r0 >= nr) return;
    const int nc = ncols[b];

    __shared__ float a_lds[RCH];
    __shared__ float cls[4 * 1024];

    const int wave = t >> 6;
    const int lane = t & 63;
    const int cbase = lane << 4;
    const bool cOK = cbase < nc;

    float w[16];
    if (cOK) {
        const float* __restrict__ csp = cs_prev + (b << 10) + cbase;
        #pragma unroll
        for (int q = 0; q < 4; ++q) {
            const float4 c4 = *reinterpret_cast<const float4*>(csp + (q << 2));
            w[4 * q + 0] = (cbase + 4 * q + 0 < nc) ? fast_rcp(c4.x) : 0.f;
            w[4 * q + 1] = (cbase + 4 * q + 1 < nc) ? fast_rcp(c4.y) : 0.f;
            w[4 * q + 2] = (cbase + 4 * q + 2 < nc) ? fast_rcp(c4.z) : 0.f;
            w[4 * q + 3] = (cbase + 4 * q + 3 < nc) ? fast_rcp(c4.w) : 0.f;
        }
    }

    #pragma unroll 1
    for (int k = 0; k < 4; ++k) {
        const int r = r0 + (wave << 2) + k;
        float s0 = 0.f, s1 = 0.f;
        if (r < nr && cOK) {
            const __half* __restrict__ erow =
                E + ((size_t)b << 19) + ((size_t)r << 10) + cbase;
            float4 p0 = *reinterpret_cast<const float4*>(erow);
            float4 p1 = *reinterpret_cast<const float4*>(erow + 8);
            const __half2* h0 = reinterpret_cast<const __half2*>(&p0);
            const __half2* h1 = reinterpret_cast<const __half2*>(&p1);
            #pragma unroll
            for (int q = 0; q < 4; ++q) {
                const float2 f = __half22float2(h0[q]);
                s0 = fmaf(f.x, w[2 * q], s0);
                s1 = fmaf(f.y, w[2 * q + 1], s1);
            }
            #pragma unroll
            for (int q = 0; q < 4; ++q) {
                const float2 f = __half22float2(h1[q]);
                s0 = fmaf(f.x, w[8 + 2 * q], s0);
                s1 = fmaf(f.y, w[8 + 2 * q + 1], s1);
            }
        }
        const float sum = wave_sum(s0 + s1);
        if (lane == 0) a_lds[(wave << 2) + k] = (r < nr) ? 1.0f / sum : 0.f;
    }
    __syncthreads();
    if (t < RCH) a[(b << 9) + r0 + t] = a_lds[t];

    phase2_col(E, a_lds, cls, b, r0, nr, nc, t, cs_cur);
}

// grid (65536), block 256. One float4 of output per thread.
__global__ __launch_bounds__(256) void out_step_f(
    const __half* __restrict__ E, const int* __restrict__ nrows,
    const int* __restrict__ ncols, const float* __restrict__ a,
    const float* __restrict__ cs, float* __restrict__ out)
{
    const int g = (blockIdx.x << 8) + threadIdx.x;  // 0..16777215
    const int b = g >> 18;
    const int rem = g & 262143;
    const int r = rem >> 8;
    const int c0 = (rem & 255) << 2;
    const int nr = nrows[b];
    const int nc = ncols[b];
    float4 o = make_float4(0.f, 0.f, 0.f, 0.f);
    if (r < nr && c0 < nc) {
        const float ar = a[(b << 9) + r];
        float2 pk = *reinterpret_cast<const float2*>(
            E + ((size_t)b << 19) + ((size_t)r << 10) + c0);
        const float2 f01 = __half22float2(reinterpret_cast<const __half2*>(&pk)[0]);
        const float2 f23 = __half22float2(reinterpret_cast<const __half2*>(&pk)[1]);
        const float4 c4 = *reinterpret_cast<const float4*>(cs + (b << 10) + c0);
        o.x = f01.x * ar * fast_rcp(c4.x);
        o.y = (c0 + 1 < nc) ? f01.y * ar * fast_rcp(c4.y) : 0.f;
        o.z = (c0 + 2 < nc) ? f23.x * ar * fast_rcp(c4.z) : 0.f;
        o.w = (c0 + 3 < nc) ? f23.y * ar * fast_rcp(c4.w) : 0.f;
    }
    reinterpret_cast<float4*>(out)[g] = o;
}

// ==================== legacy path (small workspace) =========================

__global__ __launch_bounds__(256) void row_step_lg(
    const float* __restrict__ s, const int* __restrict__ nrows,
    const int* __restrict__ ncols, const float* __restrict__ vlog,
    const int use_v, float* __restrict__ u)
{
    const int b = blockIdx.y, r = blockIdx.x;
    const int nr = nrows[b];
    if (r >= nr) return;
    const int nc = ncols[b];
    const int t = threadIdx.x, c0 = t << 2;
    float sum = 0.f;
    if (c0 < nc) {
        const float4 x = reinterpret_cast<const float4*>(
            s + ((size_t)b << 20) + ((size_t)r << 10))[t];
        float4 vv = make_float4(0.f, 0.f, 0.f, 0.f);
        if (use_v) vv = reinterpret_cast<const float4*>(vlog + ((size_t)b << 10))[t];
        sum  = (c0 + 0 < nc) ? __expf(x.x - vv.x) : 0.f;
        sum += (c0 + 1 < nc) ? __expf(x.y - vv.y) : 0.f;
        sum += (c0 + 2 < nc) ? __expf(x.z - vv.z) : 0.f;
        sum += (c0 + 3 < nc) ? __expf(x.w - vv.w) : 0.f;
    }
    #pragma unroll
    for (int off = 1; off < 64; off <<= 1) sum += __shfl_xor(sum, off);
    __shared__ float ss[4];
    if ((t & 63) == 0) ss[t >> 6] = sum;
    __syncthreads();
    if (t == 0) u[((size_t)b << 9) + r] = __logf(ss[0] + ss[1] + ss[2] + ss[3]);
}

__global__ __launch_bounds__(256) void col_step_lg(
    const float* __restrict__ s, const int* __restrict__ nrows,
    const int* __restrict__ ncols, const float* __restrict__ u,
    float* __restrict__ partial)
{
    const int b = blockIdx.z, rc = blockIdx.y;
    const int nr = nrows[b];
    const int r0 = rc << 6;
    if (r0 >= nr) return;
    const int nc = ncols[b];
    const int c = (blockIdx.x << 8) + threadIdx.x;
    float sum = 0.f;
    if (c < nc) {
        const int rend = min(r0 + 64, nr);
        const float* __restrict__ sb = s + ((size_t)b << 20) + c;
        const float* __restrict__ ub = u + ((size_t)b << 9);
        float s0 = 0.f, s1 = 0.f, s2 = 0.f, s3 = 0.f;
        int r = r0;
        for (; r + 4 <= rend; r += 4) {
            s0 += __expf(sb[(size_t)(r + 0) << 10] - ub[r + 0]);
            s1 += __expf(sb[(size_t)(r + 1) << 10] - ub[r + 1]);
            s2 += __expf(sb[(size_t)(r + 2) << 10] - ub[r + 2]);
            s3 += __expf(sb[(size_t)(r + 3) << 10] - ub[r + 3]);
        }
        for (; r < rend; ++r) s0 += __expf(sb[(size_t)r << 10] - ub[r]);
        sum = (s0 + s1) + (s2 + s3);
    }
    partial[(((size_t)b << 3) + rc) << 10 | c] = sum;
}

__global__ __launch_bounds__(256) void col_fin_lg(
    const int* __restrict__ nrows, const float* __restrict__ partial,
    float* __restrict__ vlog)
{
    const int idx = (blockIdx.x << 8) + threadIdx.x;
    const int b = idx >> 10;
    const int nch = (nrows[b] + 63) >> 6;
    const float* __restrict__ p = partial + ((size_t)(b << 3) << 10) + (idx & 1023);
    float sum = 0.f;
    for (int k = 0; k < nch; ++k) sum += p[(size_t)k << 10];
    vlog[idx] = (sum > 0.f) ? __logf(sum) : 0.f;
}

__global__ __launch_bounds__(256) void out_step_lg(
    const float* __restrict__ s, const int* __restrict__ nrows,
    const int* __restrict__ ncols, const float* __restrict__ u,
    const float* __restrict__ vlog, float* __restrict__ out)
{
    const size_t total4 = (size_t)B_DIM * 1024 * 1024 / 4;
    float4* out4 = reinterpret_cast<float4*>(out);
    const float4* s4 = reinterpret_cast<const float4*>(s);
    for (size_t i = (size_t)blockIdx.x * blockDim.x + threadIdx.x; i < total4;
         i += (size_t)gridDim.x * blockDim.x) {
        const int b = (int)(i >> 18);
        const int rem = (int)(i & 262143);
        const int r = rem >> 8;
        const int c0 = (rem & 255) << 2;
        const int nr = nrows[b], nc = ncols[b];
        float4 o;
        if (r >= nr || c0 >= nc) {
            o = make_float4(0.f, 0.f, 0.f, 0.f);
        } else {
            float4 x = s4[i];
            const float ur = u[((size_t)b << 9) + r];
            const float* vb = vlog + ((size_t)b << 10);
            o.x = (c0 + 0 < nc) ? __expf(x.x - ur - vb[c0 + 0]) : 0.f;
            o.y = (c0 + 1 < nc) ? __expf(x.y - ur - vb[c0 + 1]) : 0.f;
            o.z = (c0 + 2 < nc) ? __expf(x.z - ur - vb[c0 + 2]) : 0.f;
            o.w = (c0 + 3 < nc) ? __expf(x.w - ur - vb[c0 + 3]) : 0.f;
        }
        out4[i] = o;
    }
}

// ============================================================================

extern "C" void kernel_launch(void* const* d_in, const int* in_sizes, int n_in,
                              void* d_out, int out_size, void* d_ws, size_t ws_size,
                              hipStream_t stream) {
    const float* s = (const float*)d_in[0];
    const int* nrows = (const int*)d_in[1];
    const int* ncols = (const int*)d_in[2];
    float* out = (float*)d_out;

    const size_t E_BYTES = (size_t)B_DIM * 512 * 1024 * 2;   // 64 MiB fp16
    const size_t CS_ELEMS = (size_t)B_DIM * 1024;
    const size_t NEED = E_BYTES + (size_t)B_DIM * 512 * 4 + 3 * CS_ELEMS * 4;

    if (ws_size >= NEED) {
        __half* E = (__half*)d_ws;
        float* a = (float*)((char*)d_ws + E_BYTES);
        float* cs0 = a + B_DIM * 512;
        float* cs1 = cs0 + CS_ELEMS;
        float* cs2 = cs1 + CS_ELEMS;

        hipMemsetAsync(cs0, 0, CS_ELEMS * sizeof(float), stream);

        const dim3 grid(NCH, B_DIM);
        // pair i: prev=cs[(i+2)%3], cur=cs[i%3], next=cs[(i+1)%3]
        pair_first<<<grid, 512, 0, stream>>>(s, nrows, ncols, E, a, cs0, cs1);
        pair_mid<<<grid, 512, 0, stream>>>(E, nrows, ncols, cs0, a, cs1, cs2);
        pair_mid<<<grid, 512, 0, stream>>>(E, nrows, ncols, cs1, a, cs2, cs0);
        pair_mid<<<grid, 512, 0, stream>>>(E, nrows, ncols, cs2, a, cs0, cs1);
        pair_mid<<<grid, 512, 0, stream>>>(E, nrows, ncols, cs0, a, cs1, cs2);
        out_step_f<<<65536, 256, 0, stream>>>(E, nrows, ncols, a, cs1, out);
    } else {
        // legacy log-space path (needs ~2.4 MiB)
        float* u = (float*)d_ws;
        float* vlog = u + (size_t)B_DIM * 512;
        float* partial = vlog + (size_t)B_DIM * 1024;
        const dim3 rowGrid(512, B_DIM);
        const dim3 colGrid(4, 8, B_DIM);
        for (int it = 0; it < 5; ++it) {
            row_step_lg<<<rowGrid, 256, 0, stream>>>(s, nrows, ncols, vlog, it, u);
            col_step_lg<<<colGrid, 256, 0, stream>>>(s, nrows, ncols, u, partial);
            col_fin_lg<<<256, 256, 0, stream>>>(nrows, partial, vlog);
        }
        out_step_lg<<<4096, 256, 0, stream>>>(s, nrows, ncols, u, vlog, out);
    }
}